// Round 1
// baseline (2484.628 us; speedup 1.0000x reference)
//
#include <hip/hip_runtime.h>

typedef long long i64;

#define NB   64      // batch
#define NS   20      // seq
#define NV   30000   // vocab
#define NE   256     // embed
#define NH   512     // hidden
#define NF   2048    // feat
#define NP   49      // spatial
#define NG   2048    // 4*NH

__device__ __forceinline__ float sigm(float x) { return 1.f / (1.f + expf(-x)); }

// ---------------- init: h_init = tanh(cnn@Whi.T+bhi), c_init = tanh(cnn@Wci.T+bci)
// writes h_init into xa[b][512:1024] (h0 slot) and xb[b][512:1024] (h1 slot); c0,c1.
__global__ __launch_bounds__(256) void init_hc(
    const float* __restrict__ cnn, const float* __restrict__ Whi, const float* __restrict__ bhi,
    const float* __restrict__ Wci, const float* __restrict__ bci,
    float* __restrict__ xa, float* __restrict__ xb, float* __restrict__ c0, float* __restrict__ c1)
{
    int b = blockIdx.x, tid = threadIdx.x;
    __shared__ float xsh[NH];
    xsh[tid] = cnn[(i64)b * NH + tid];
    xsh[tid + 256] = cnn[(i64)b * NH + 256 + tid];
    __syncthreads();
    #pragma unroll
    for (int hh = 0; hh < 2; hh++) {
        int h = tid + hh * 256;
        const float4* wh = (const float4*)(Whi + (i64)h * NH);
        const float4* wc = (const float4*)(Wci + (i64)h * NH);
        const float4* xv = (const float4*)xsh;
        float ah = bhi[h], ac = bci[h];
        for (int k = 0; k < NH / 4; k++) {
            float4 x = xv[k], a = wh[k], c = wc[k];
            ah += a.x * x.x + a.y * x.y + a.z * x.z + a.w * x.w;
            ac += c.x * x.x + c.y * x.y + c.z * x.z + c.w * x.w;
        }
        float th = tanhf(ah), tc = tanhf(ac);
        xa[(i64)b * 1024 + 512 + h] = th;
        xb[(i64)b * 1024 + 512 + h] = th;
        c0[(i64)b * NH + h] = tc;
        c1[(i64)b * NH + h] = tc;
    }
}

// ---------------- embedding gather: xs[t][b][e], padding_idx=0 -> 0
__global__ __launch_bounds__(256) void embed_kernel(
    const int* __restrict__ ids, const float* __restrict__ table, float* __restrict__ xs)
{
    int blk = blockIdx.x;            // t*NB + b
    int t = blk / NB, b = blk % NB;
    int id = ids[(i64)b * NS + t];
    float v = (id == 0) ? 0.f : table[(i64)id * NE + threadIdx.x];
    xs[(i64)blk * NE + threadIdx.x] = v;
}

// ---------------- proj GEMM: proj[m= b*49+p][n] = sum_f attn[b][f][p]*Wf[n][f] + bf[n]
// M=3136, N=512, K=2048.  BM=128, BN=64, thread 8x4.
__global__ __launch_bounds__(256) void proj_kernel(
    const float* __restrict__ af, const float* __restrict__ Wf,
    const float* __restrict__ bf, float* __restrict__ proj)
{
    __shared__ float As[16][132];
    __shared__ float Bs[16][68];
    const int tid = threadIdx.x;
    const int bn = blockIdx.x * 64;
    const int bm = blockIdx.y * 128;
    const int tn = (tid & 15) * 4, tm = (tid >> 4) * 8;
    const int lk = tid & 15, lr = tid >> 4;      // B loader
    const int lm = tid & 127, lkq = tid >> 7;    // A loader (coalesced along p)
    const int m_g = bm + lm;
    const int bA = m_g / NP, pA = m_g - bA * NP;
    float acc[8][4] = {};
    for (int k0 = 0; k0 < NF; k0 += 16) {
        #pragma unroll
        for (int i = 0; i < 8; i++) {
            int kk = lkq * 8 + i;
            As[kk][lm] = (m_g < NB * NP) ? af[(i64)bA * (NF * NP) + (i64)(k0 + kk) * NP + pA] : 0.f;
        }
        #pragma unroll
        for (int i = 0; i < 4; i++) {
            int n = bn + lr + i * 16;
            Bs[lk][lr + i * 16] = Wf[(i64)n * NF + k0 + lk];
        }
        __syncthreads();
        #pragma unroll
        for (int kk = 0; kk < 16; kk++) {
            float a[8], bv[4];
            #pragma unroll
            for (int i = 0; i < 8; i++) a[i] = As[kk][tm + i];
            #pragma unroll
            for (int j = 0; j < 4; j++) bv[j] = Bs[kk][tn + j];
            #pragma unroll
            for (int i = 0; i < 8; i++)
                #pragma unroll
                for (int j = 0; j < 4; j++) acc[i][j] += a[i] * bv[j];
        }
        __syncthreads();
    }
    #pragma unroll
    for (int i = 0; i < 8; i++) {
        int m = bm + tm + i;
        if (m < NB * NP) {
            #pragma unroll
            for (int j = 0; j < 4; j++) {
                int n = bn + tn + j;
                proj[(i64)m * NH + n] = acc[i][j] + bf[n];
            }
        }
    }
}

// ---------------- generic GEMM  C = A @ B.T (+bias1+bias2), BM=128 BN=64, thread 8x4
// outmode 0: C[m*ldc+n]; outmode 1: C[(m%64)*S*V + (m/64)*V + n] (phase-C remap)
struct GArgs {
    const float* A; i64 lda;
    const float* Bm; i64 ldb;
    const float* bias1; const float* bias2;
    float* C; i64 ldc;
    int M, N, K, outmode;
};

__global__ __launch_bounds__(256) void gemm128_kernel(GArgs g)
{
    __shared__ float As[16][132];
    __shared__ float Bs[16][68];
    const int tid = threadIdx.x;
    const int bn = blockIdx.x * 64;
    const int bm = blockIdx.y * 128;
    const int tn = (tid & 15) * 4, tm = (tid >> 4) * 8;
    const int lk = tid & 15, lr = tid >> 4;
    float acc[8][4] = {};
    for (int k0 = 0; k0 < g.K; k0 += 16) {
        #pragma unroll
        for (int i = 0; i < 8; i++) {
            int m = bm + lr + i * 16;
            As[lk][lr + i * 16] = (m < g.M) ? g.A[(i64)m * g.lda + k0 + lk] : 0.f;
        }
        #pragma unroll
        for (int i = 0; i < 4; i++) {
            int n = bn + lr + i * 16;
            Bs[lk][lr + i * 16] = (n < g.N) ? g.Bm[(i64)n * g.ldb + k0 + lk] : 0.f;
        }
        __syncthreads();
        #pragma unroll
        for (int kk = 0; kk < 16; kk++) {
            float a[8], bv[4];
            #pragma unroll
            for (int i = 0; i < 8; i++) a[i] = As[kk][tm + i];
            #pragma unroll
            for (int j = 0; j < 4; j++) bv[j] = Bs[kk][tn + j];
            #pragma unroll
            for (int i = 0; i < 8; i++)
                #pragma unroll
                for (int j = 0; j < 4; j++) acc[i][j] += a[i] * bv[j];
        }
        __syncthreads();
    }
    #pragma unroll
    for (int i = 0; i < 8; i++) {
        int m = bm + tm + i;
        if (m >= g.M) continue;
        int n0 = bn + tn;
        float v[4];
        #pragma unroll
        for (int j = 0; j < 4; j++) {
            v[j] = acc[i][j];
            int n = n0 + j;
            if (n < g.N) {
                if (g.bias1) v[j] += g.bias1[n];
                if (g.bias2) v[j] += g.bias2[n];
            }
        }
        i64 base = g.outmode ? (i64)(m & 63) * ((i64)NS * NV) + (i64)(m >> 6) * NV + n0
                             : (i64)m * g.ldc + n0;
        if (n0 + 3 < g.N) {
            *(float4*)&g.C[base] = make_float4(v[0], v[1], v[2], v[3]);
        } else {
            #pragma unroll
            for (int j = 0; j < 4; j++)
                if (n0 + j < g.N) g.C[base + j] = v[j];
        }
    }
}

// ---------------- attention (one block per b): ha = h1@Wa.T+ba; softmax(ha . proj); ctx
__global__ __launch_bounds__(256) void attn_kernel(
    const float* __restrict__ xb, const float* __restrict__ Wa, const float* __restrict__ ba,
    const float* __restrict__ proj, float* __restrict__ xa)
{
    int b = blockIdx.x, tid = threadIdx.x;
    __shared__ float h1s[NH];
    __shared__ float has[NH];
    __shared__ float sw[64];
    h1s[tid] = xb[(i64)b * 1024 + 512 + tid];
    h1s[tid + 256] = xb[(i64)b * 1024 + 768 + tid];
    __syncthreads();
    #pragma unroll
    for (int hh = 0; hh < 2; hh++) {
        int h = tid + hh * 256;
        const float4* w4 = (const float4*)(Wa + (i64)h * NH);
        const float4* h4 = (const float4*)h1s;
        float acc = ba[h];
        for (int k = 0; k < NH / 4; k++) {
            float4 a = w4[k], x = h4[k];
            acc += a.x * x.x + a.y * x.y + a.z * x.z + a.w * x.w;
        }
        has[h] = acc;
    }
    __syncthreads();
    int wv = tid >> 6, ln = tid & 63;
    for (int p = wv; p < NP; p += 4) {
        const float* pp = proj + ((i64)b * NP + p) * NH;
        float s = 0.f;
        #pragma unroll
        for (int j = 0; j < NH / 64; j++) s += has[ln + j * 64] * pp[ln + j * 64];
        #pragma unroll
        for (int off = 32; off > 0; off >>= 1) s += __shfl_down(s, off, 64);
        if (ln == 0) sw[p] = s;
    }
    __syncthreads();
    if (tid < 64) {
        float v = (tid < NP) ? sw[tid] : -3.4e38f;
        float m = v;
        #pragma unroll
        for (int off = 32; off > 0; off >>= 1) m = fmaxf(m, __shfl_xor(m, off, 64));
        float e = (tid < NP) ? expf(v - m) : 0.f;
        float s = e;
        #pragma unroll
        for (int off = 32; off > 0; off >>= 1) s += __shfl_xor(s, off, 64);
        if (tid < NP) sw[tid] = e / s;
    }
    __syncthreads();
    #pragma unroll
    for (int hh = 0; hh < 2; hh++) {
        int h = tid + hh * 256;
        float acc = 0.f;
        for (int p = 0; p < NP; p++) acc += sw[p] * proj[((i64)b * NP + p) * NH + h];
        xa[(i64)b * 1024 + h] = acc;
    }
}

// ---------------- per-step gate GEMM: gpart[z][b][n] = partial over K-chunk of 128
// A[b][k] (lda=1024):  k<512 half uses B1 (+bo1), k>=512 half uses B2.
struct LArgs {
    const float* A;
    const float* B1; i64 ldb1; int bo1;
    const float* B2; i64 ldb2;
    float* gpart;
};

__global__ __launch_bounds__(256) void lstm_gemm_kernel(LArgs g)
{
    __shared__ float As[16][68];
    __shared__ float Bs[16][68];
    const int tid = threadIdx.x;
    const int bn = blockIdx.x * 64;
    const int kz = blockIdx.z;
    const int tn = (tid & 15) * 4, tm = (tid >> 4) * 4;
    const int lk = tid & 15, lr = tid >> 4;
    float acc[4][4] = {};
    for (int k0 = kz * 128; k0 < kz * 128 + 128; k0 += 16) {
        #pragma unroll
        for (int i = 0; i < 4; i++) {
            int m = lr + i * 16;
            As[lk][lr + i * 16] = g.A[(i64)m * 1024 + k0 + lk];
        }
        int k = k0 + lk;
        const float* bp = (k < 512) ? (g.B1 + g.bo1 + k) : (g.B2 + (k - 512));
        i64 ldb = (k < 512) ? g.ldb1 : g.ldb2;
        #pragma unroll
        for (int i = 0; i < 4; i++) {
            int n = bn + lr + i * 16;
            Bs[lk][lr + i * 16] = bp[(i64)n * ldb];
        }
        __syncthreads();
        #pragma unroll
        for (int kk = 0; kk < 16; kk++) {
            float a[4], bv[4];
            #pragma unroll
            for (int i = 0; i < 4; i++) a[i] = As[kk][tm + i];
            #pragma unroll
            for (int j = 0; j < 4; j++) bv[j] = Bs[kk][tn + j];
            #pragma unroll
            for (int i = 0; i < 4; i++)
                #pragma unroll
                for (int j = 0; j < 4; j++) acc[i][j] += a[i] * bv[j];
        }
        __syncthreads();
    }
    float* out = g.gpart + (i64)kz * NB * NG;
    #pragma unroll
    for (int i = 0; i < 4; i++) {
        *(float4*)&out[(i64)(tm + i) * NG + bn + tn] =
            make_float4(acc[i][0], acc[i][1], acc[i][2], acc[i][3]);
    }
}

// ---------------- gate finalize: sum 8 partials (+xpre or +biases), activations, state update
__global__ __launch_bounds__(512) void lstm_fin_kernel(
    const float* __restrict__ gpart, const float* __restrict__ xpre_t,
    const float* __restrict__ bih, const float* __restrict__ bhh,
    float* __restrict__ cbuf, float* __restrict__ hA, float* __restrict__ hB,
    float* __restrict__ h1all_t)
{
    int b = blockIdx.x, h = threadIdx.x;
    float gi, gf, gg, go;
    if (xpre_t) {
        const float* xp = xpre_t + (i64)b * NG;
        gi = xp[h]; gf = xp[h + 512]; gg = xp[h + 1024]; go = xp[h + 1536];
    } else {
        gi = bih[h] + bhh[h];
        gf = bih[h + 512] + bhh[h + 512];
        gg = bih[h + 1024] + bhh[h + 1024];
        go = bih[h + 1536] + bhh[h + 1536];
    }
    #pragma unroll
    for (int z = 0; z < 8; z++) {
        const float* gp = gpart + ((i64)z * NB + b) * NG;
        gi += gp[h]; gf += gp[h + 512]; gg += gp[h + 1024]; go += gp[h + 1536];
    }
    float i = sigm(gi), f = sigm(gf), g2 = tanhf(gg), o = sigm(go);
    float c = f * cbuf[(i64)b * NH + h] + i * g2;
    cbuf[(i64)b * NH + h] = c;
    float hn = o * tanhf(c);
    hA[(i64)b * 1024 + h] = hn;
    if (hB) hB[(i64)b * 1024 + h] = hn;
    if (h1all_t) h1all_t[(i64)b * NH + h] = hn;
}

// ---------------- final states: h_final (2,B,H) then c_final (2,B,H)
__global__ __launch_bounds__(512) void final_copy(
    const float* __restrict__ xb, const float* __restrict__ c0, const float* __restrict__ c1,
    float* __restrict__ out)
{
    int b = blockIdx.x, h = threadIdx.x;
    const i64 OB = (i64)NB * NS * NV;
    out[OB + (i64)b * NH + h] = xb[(i64)b * 1024 + h];                       // h0
    out[OB + (i64)NB * NH + (i64)b * NH + h] = xb[(i64)b * 1024 + 512 + h];  // h1
    out[OB + 2 * (i64)NB * NH + (i64)b * NH + h] = c0[(i64)b * NH + h];      // c0
    out[OB + 3 * (i64)NB * NH + (i64)b * NH + h] = c1[(i64)b * NH + h];      // c1
}

extern "C" void kernel_launch(void* const* d_in, const int* in_sizes, int n_in,
                              void* d_out, int out_size, void* d_ws, size_t ws_size,
                              hipStream_t stream)
{
    (void)in_sizes; (void)n_in; (void)out_size; (void)ws_size;
    const int*   word_ids = (const int*)d_in[0];
    const float* cnn   = (const float*)d_in[1];
    const float* attnf = (const float*)d_in[2];
    const float* table = (const float*)d_in[3];
    const float* Wf    = (const float*)d_in[4];
    const float* bfp   = (const float*)d_in[5];
    const float* Wa    = (const float*)d_in[6];
    const float* ba    = (const float*)d_in[7];
    const float* Wih0  = (const float*)d_in[8];
    const float* Whh0  = (const float*)d_in[9];
    const float* bih0  = (const float*)d_in[10];
    const float* bhh0  = (const float*)d_in[11];
    const float* Wih1  = (const float*)d_in[12];
    const float* Whh1  = (const float*)d_in[13];
    const float* bih1  = (const float*)d_in[14];
    const float* bhh1  = (const float*)d_in[15];
    const float* Whi   = (const float*)d_in[16];
    const float* bhi   = (const float*)d_in[17];
    const float* Wci   = (const float*)d_in[18];
    const float* bci   = (const float*)d_in[19];
    const float* Wout  = (const float*)d_in[20];
    const float* bout  = (const float*)d_in[21];
    float* out = (float*)d_out;

    float* ws    = (float*)d_ws;
    float* proj  = ws;                    // 3136*512      = 1,605,632
    float* xs    = proj + 1605632;        // 1280*256      =   327,680
    float* xpre  = xs + 327680;           // 1280*2048     = 2,621,440
    float* xa    = xpre + 2621440;        // 64*1024 [ctx|h0]
    float* xb    = xa + 65536;            // 64*1024 [h0n|h1]
    float* c0    = xb + 65536;            // 64*512
    float* c1    = c0 + 32768;            // 64*512
    float* gpart = c1 + 32768;            // 8*64*2048     = 1,048,576
    float* h1all = gpart + 1048576;       // 20*64*512     =   655,360

    init_hc<<<dim3(NB), dim3(256), 0, stream>>>(cnn, Whi, bhi, Wci, bci, xa, xb, c0, c1);
    proj_kernel<<<dim3(8, 25), dim3(256), 0, stream>>>(attnf, Wf, bfp, proj);
    embed_kernel<<<dim3(NS * NB), dim3(256), 0, stream>>>(word_ids, table, xs);

    // xpre[t*B+b][g] = xs @ Wih0[:, :256].T + (b_ih0 + b_hh0)
    GArgs gx{xs, NE, Wih0, NE + NH, bih0, bhh0, xpre, NG, NS * NB, NG, NE, 0};
    gemm128_kernel<<<dim3(NG / 64, 10), dim3(256), 0, stream>>>(gx);

    for (int t = 0; t < NS; t++) {
        attn_kernel<<<dim3(NB), dim3(256), 0, stream>>>(xb, Wa, ba, proj, xa);
        // gates0 partial: A=[ctx|h0], B1=Wih0 (ctx cols, offset 256), B2=Whh0
        LArgs l0{xa, Wih0, NE + NH, NE, Whh0, NH, gpart};
        lstm_gemm_kernel<<<dim3(NG / 64, 1, 8), dim3(256), 0, stream>>>(l0);
        lstm_fin_kernel<<<dim3(NB), dim3(512), 0, stream>>>(
            gpart, xpre + (i64)t * NB * NG, (const float*)nullptr, (const float*)nullptr,
            c0, xb, xa + 512, (float*)nullptr);
        // gates1 partial: A=[h0n|h1], B1=Wih1, B2=Whh1
        LArgs l1{xb, Wih1, NH, 0, Whh1, NH, gpart};
        lstm_gemm_kernel<<<dim3(NG / 64, 1, 8), dim3(256), 0, stream>>>(l1);
        lstm_fin_kernel<<<dim3(NB), dim3(512), 0, stream>>>(
            gpart, (const float*)nullptr, bih1, bhh1,
            c1, xb + 512, (float*)nullptr, h1all + (i64)t * NB * NH);
    }

    // deferred output projection: (S*B, V, K=H), remapped write to (B,S,V)
    GArgs go{h1all, NH, Wout, NH, bout, nullptr, out, NV, NS * NB, NV, NH, 1};
    gemm128_kernel<<<dim3((NV + 63) / 64, 10), dim3(256), 0, stream>>>(go);

    final_copy<<<dim3(NB), dim3(512), 0, stream>>>(xb, c0, c1, out);
}

// Round 2
// 1926.556 us; speedup vs baseline: 1.2897x; 1.2897x over previous
//
#include <hip/hip_runtime.h>
#include <hip/hip_bf16.h>

typedef long long i64;

#define NB   64      // batch
#define NS   20      // seq
#define NV   30000   // vocab
#define NE   256     // embed
#define NH   512     // hidden
#define NF   2048    // feat
#define NP   49      // spatial
#define NG   2048    // 4*NH

typedef __attribute__((ext_vector_type(8))) __bf16 bf16x8;
typedef __attribute__((ext_vector_type(4))) float  f32x4;

__device__ __forceinline__ float sigm(float x) { return 1.f / (1.f + expf(-x)); }

__device__ __forceinline__ void gload_lds16(const void* g, void* l) {
    __builtin_amdgcn_global_load_lds(
        (const __attribute__((address_space(1))) void*)g,
        (__attribute__((address_space(3))) void*)l, 16, 0, 0);
}

// ---------------- init: h_init = tanh(cnn@Whi.T+bhi), c_init = tanh(cnn@Wci.T+bci)
__global__ __launch_bounds__(256) void init_hc(
    const float* __restrict__ cnn, const float* __restrict__ Whi, const float* __restrict__ bhi,
    const float* __restrict__ Wci, const float* __restrict__ bci,
    float* __restrict__ xa, float* __restrict__ xb, float* __restrict__ c0, float* __restrict__ c1)
{
    int b = blockIdx.x, tid = threadIdx.x;
    __shared__ float xsh[NH];
    xsh[tid] = cnn[(i64)b * NH + tid];
    xsh[tid + 256] = cnn[(i64)b * NH + 256 + tid];
    __syncthreads();
    #pragma unroll
    for (int hh = 0; hh < 2; hh++) {
        int h = tid + hh * 256;
        const float4* wh = (const float4*)(Whi + (i64)h * NH);
        const float4* wc = (const float4*)(Wci + (i64)h * NH);
        const float4* xv = (const float4*)xsh;
        float ah = bhi[h], ac = bci[h];
        for (int k = 0; k < NH / 4; k++) {
            float4 x = xv[k], a = wh[k], c = wc[k];
            ah += a.x * x.x + a.y * x.y + a.z * x.z + a.w * x.w;
            ac += c.x * x.x + c.y * x.y + c.z * x.z + c.w * x.w;
        }
        float th = tanhf(ah), tc = tanhf(ac);
        xa[(i64)b * 1024 + 512 + h] = th;
        xb[(i64)b * 1024 + 512 + h] = th;
        c0[(i64)b * NH + h] = tc;
        c1[(i64)b * NH + h] = tc;
    }
}

// ---------------- embedding gather
__global__ __launch_bounds__(256) void embed_kernel(
    const int* __restrict__ ids, const float* __restrict__ table, float* __restrict__ xs)
{
    int blk = blockIdx.x;            // t*NB + b
    int t = blk / NB, b = blk % NB;
    int id = ids[(i64)b * NS + t];
    float v = (id == 0) ? 0.f : table[(i64)id * NE + threadIdx.x];
    xs[(i64)blk * NE + threadIdx.x] = v;
}

// ---------------- fp32 -> bf16 cast (8 elems/thread)
__global__ __launch_bounds__(256) void cast_bf16_kernel(
    const float* __restrict__ in, __hip_bfloat16* __restrict__ outp, int n8)
{
    int i = blockIdx.x * 256 + threadIdx.x;
    if (i >= n8) return;
    const float4* p = (const float4*)(in + (i64)i * 8);
    float4 a = p[0], b = p[1];
    __hip_bfloat16 v[8];
    v[0] = __float2bfloat16(a.x); v[1] = __float2bfloat16(a.y);
    v[2] = __float2bfloat16(a.z); v[3] = __float2bfloat16(a.w);
    v[4] = __float2bfloat16(b.x); v[5] = __float2bfloat16(b.y);
    v[6] = __float2bfloat16(b.z); v[7] = __float2bfloat16(b.w);
    *(float4*)(outp + (i64)i * 8) = *(float4*)v;
}

// ---------------- proj GEMM: proj[b*49+p][n] = sum_f attn[b][f][p]*Wf[n][f] + bf[n]
__global__ __launch_bounds__(256) void proj_kernel(
    const float* __restrict__ af, const float* __restrict__ Wf,
    const float* __restrict__ bf, float* __restrict__ proj)
{
    __shared__ float As[16][132];
    __shared__ float Bs[16][68];
    const int tid = threadIdx.x;
    const int bn = blockIdx.x * 64;
    const int bm = blockIdx.y * 128;
    const int tn = (tid & 15) * 4, tm = (tid >> 4) * 8;
    const int lk = tid & 15, lr = tid >> 4;
    const int lm = tid & 127, lkq = tid >> 7;
    const int m_g = bm + lm;
    const int bA = m_g / NP, pA = m_g - bA * NP;
    float acc[8][4] = {};
    for (int k0 = 0; k0 < NF; k0 += 16) {
        #pragma unroll
        for (int i = 0; i < 8; i++) {
            int kk = lkq * 8 + i;
            As[kk][lm] = (m_g < NB * NP) ? af[(i64)bA * (NF * NP) + (i64)(k0 + kk) * NP + pA] : 0.f;
        }
        #pragma unroll
        for (int i = 0; i < 4; i++) {
            int n = bn + lr + i * 16;
            Bs[lk][lr + i * 16] = Wf[(i64)n * NF + k0 + lk];
        }
        __syncthreads();
        #pragma unroll
        for (int kk = 0; kk < 16; kk++) {
            float a[8], bv[4];
            #pragma unroll
            for (int i = 0; i < 8; i++) a[i] = As[kk][tm + i];
            #pragma unroll
            for (int j = 0; j < 4; j++) bv[j] = Bs[kk][tn + j];
            #pragma unroll
            for (int i = 0; i < 8; i++)
                #pragma unroll
                for (int j = 0; j < 4; j++) acc[i][j] += a[i] * bv[j];
        }
        __syncthreads();
    }
    #pragma unroll
    for (int i = 0; i < 8; i++) {
        int m = bm + tm + i;
        if (m < NB * NP) {
            #pragma unroll
            for (int j = 0; j < 4; j++) {
                int n = bn + tn + j;
                proj[(i64)m * NH + n] = acc[i][j] + bf[n];
            }
        }
    }
}

// ---------------- generic fp32 GEMM C = A @ B.T (+bias), fallback / small prep GEMMs
struct GArgs {
    const float* A; i64 lda;
    const float* Bm; i64 ldb;
    const float* bias1; const float* bias2;
    float* C; i64 ldc;
    int M, N, K, outmode;
};

__global__ __launch_bounds__(256) void gemm128_kernel(GArgs g)
{
    __shared__ float As[16][132];
    __shared__ float Bs[16][68];
    const int tid = threadIdx.x;
    const int bn = blockIdx.x * 64;
    const int bm = blockIdx.y * 128;
    const int tn = (tid & 15) * 4, tm = (tid >> 4) * 8;
    const int lk = tid & 15, lr = tid >> 4;
    float acc[8][4] = {};
    for (int k0 = 0; k0 < g.K; k0 += 16) {
        #pragma unroll
        for (int i = 0; i < 8; i++) {
            int m = bm + lr + i * 16;
            As[lk][lr + i * 16] = (m < g.M) ? g.A[(i64)m * g.lda + k0 + lk] : 0.f;
        }
        #pragma unroll
        for (int i = 0; i < 4; i++) {
            int n = bn + lr + i * 16;
            Bs[lk][lr + i * 16] = (n < g.N) ? g.Bm[(i64)n * g.ldb + k0 + lk] : 0.f;
        }
        __syncthreads();
        #pragma unroll
        for (int kk = 0; kk < 16; kk++) {
            float a[8], bv[4];
            #pragma unroll
            for (int i = 0; i < 8; i++) a[i] = As[kk][tm + i];
            #pragma unroll
            for (int j = 0; j < 4; j++) bv[j] = Bs[kk][tn + j];
            #pragma unroll
            for (int i = 0; i < 8; i++)
                #pragma unroll
                for (int j = 0; j < 4; j++) acc[i][j] += a[i] * bv[j];
        }
        __syncthreads();
    }
    #pragma unroll
    for (int i = 0; i < 8; i++) {
        int m = bm + tm + i;
        if (m >= g.M) continue;
        int n0 = bn + tn;
        float v[4];
        #pragma unroll
        for (int j = 0; j < 4; j++) {
            v[j] = acc[i][j];
            int n = n0 + j;
            if (n < g.N) {
                if (g.bias1) v[j] += g.bias1[n];
                if (g.bias2) v[j] += g.bias2[n];
            }
        }
        i64 base = g.outmode ? (i64)(m & 63) * ((i64)NS * NV) + (i64)(m >> 6) * NV + n0
                             : (i64)m * g.ldc + n0;
        if (n0 + 3 < g.N) {
            *(float4*)&g.C[base] = make_float4(v[0], v[1], v[2], v[3]);
        } else {
            #pragma unroll
            for (int j = 0; j < 4; j++)
                if (n0 + j < g.N) g.C[base + j] = v[j];
        }
    }
}

// ---------------- phase-C bf16 MFMA GEMM: out[(m&63)][m>>6][n] = A[m][:] . W[n][:] + bout[n]
// A = h1b (1280 x 512 bf16), W = Woutb (30000 x 512 bf16). BM=BN=128, BK=64.
// grid: 2350 blocks (10 M-tiles fast inside each N-tile), bijective XCD swizzle.
__global__ __launch_bounds__(256) void gemm_out_mfma(
    const __hip_bfloat16* __restrict__ Ab_, const __hip_bfloat16* __restrict__ Wb_,
    const float* __restrict__ bout, float* __restrict__ out)
{
    __shared__ __bf16 As[128 * 64];
    __shared__ __bf16 Bs[128 * 64];
    const __bf16* Ab = (const __bf16*)Ab_;
    const __bf16* Wb = (const __bf16*)Wb_;

    // bijective XCD swizzle: nwg=2350, q=293, r=6
    int orig = blockIdx.x;
    int xcd = orig & 7, local = orig >> 3;
    int wgid = (xcd < 6 ? xcd * 294 : 6 * 294 + (xcd - 6) * 293) + local;
    const int bn = (wgid / 10) * 128;
    const int bm = (wgid % 10) * 128;

    const int tid = threadIdx.x;
    const int w = tid >> 6;          // wave 0..3
    const int l = tid & 63;          // lane
    const int wr = w >> 1, wc = w & 1;

    f32x4 acc[4][4] = {};

    for (int k0 = 0; k0 < NH; k0 += 64) {
        // stage A-tile 128x64 and B-tile 128x64 (16B per lane, 4 rounds each)
        #pragma unroll
        for (int r = 0; r < 4; r++) {
            int rowA = r * 32 + w * 8 + (l >> 3);
            const __bf16* srcA = Ab + (i64)(bm + rowA) * NH + k0 + (l & 7) * 8;
            gload_lds16(srcA, &As[(r * 32 + w * 8) * 64]);
            int rowBn = bn + r * 32 + w * 8 + (l >> 3);
            if (rowBn >= NV) rowBn = 0;   // safe garbage; those cols never stored
            const __bf16* srcB = Wb + (i64)rowBn * NH + k0 + (l & 7) * 8;
            gload_lds16(srcB, &Bs[(r * 32 + w * 8) * 64]);
        }
        __syncthreads();
        #pragma unroll
        for (int kk = 0; kk < 2; kk++) {
            bf16x8 af[4], bfr[4];
            #pragma unroll
            for (int mr = 0; mr < 4; mr++)
                af[mr] = *(const bf16x8*)&As[(wr * 64 + mr * 16 + (l & 15)) * 64 + kk * 32 + (l >> 4) * 8];
            #pragma unroll
            for (int nr = 0; nr < 4; nr++)
                bfr[nr] = *(const bf16x8*)&Bs[(wc * 64 + nr * 16 + (l & 15)) * 64 + kk * 32 + (l >> 4) * 8];
            #pragma unroll
            for (int mr = 0; mr < 4; mr++)
                #pragma unroll
                for (int nr = 0; nr < 4; nr++)
                    acc[mr][nr] = __builtin_amdgcn_mfma_f32_16x16x32_bf16(af[mr], bfr[nr], acc[mr][nr], 0, 0, 0);
        }
        __syncthreads();
    }

    // epilogue: C/D layout col=lane&15, row=(lane>>4)*4+j
    #pragma unroll
    for (int nr = 0; nr < 4; nr++) {
        int n = bn + wc * 64 + nr * 16 + (l & 15);
        if (n >= NV) continue;
        float bv = bout[n];
        #pragma unroll
        for (int mr = 0; mr < 4; mr++) {
            int mbase = bm + wr * 64 + mr * 16 + (l >> 4) * 4;
            #pragma unroll
            for (int j = 0; j < 4; j++) {
                int m = mbase + j;   // m = t*64+b
                out[(i64)(m & 63) * ((i64)NS * NV) + (i64)(m >> 6) * NV + n] = acc[mr][nr][j] + bv;
            }
        }
    }
}

// ---------------- fused: [fin1 of prev step] + attention
__global__ __launch_bounds__(256) void attn_fused(
    const float* __restrict__ gpart,      // null at t=0 -> skip fin
    const float* __restrict__ bih1, const float* __restrict__ bhh1,
    float* __restrict__ c1, float* __restrict__ xb,
    float* __restrict__ h1f, __hip_bfloat16* __restrict__ h1b,   // one may be null
    const float* __restrict__ Wa, const float* __restrict__ ba,
    const float* __restrict__ proj, float* __restrict__ xa)
{
    int b = blockIdx.x, tid = threadIdx.x;
    __shared__ float h1s[NH];
    __shared__ float has[NH];
    __shared__ float sw[64];
    if (gpart) {
        #pragma unroll
        for (int hh = 0; hh < 2; hh++) {
            int h = tid + hh * 256;
            float gi = bih1[h] + bhh1[h];
            float gf = bih1[h + 512] + bhh1[h + 512];
            float gg = bih1[h + 1024] + bhh1[h + 1024];
            float go = bih1[h + 1536] + bhh1[h + 1536];
            #pragma unroll
            for (int z = 0; z < 8; z++) {
                const float* gp = gpart + ((i64)z * NB + b) * NG;
                gi += gp[h]; gf += gp[h + 512]; gg += gp[h + 1024]; go += gp[h + 1536];
            }
            float i = sigm(gi), f = sigm(gf), g2 = tanhf(gg), o = sigm(go);
            float c = f * c1[(i64)b * NH + h] + i * g2;
            c1[(i64)b * NH + h] = c;
            float hn = o * tanhf(c);
            h1s[h] = hn;
            xb[(i64)b * 1024 + 512 + h] = hn;
            if (h1f) h1f[(i64)b * NH + h] = hn;
            if (h1b) h1b[(i64)b * NH + h] = __float2bfloat16(hn);
        }
    } else {
        h1s[tid] = xb[(i64)b * 1024 + 512 + tid];
        h1s[tid + 256] = xb[(i64)b * 1024 + 768 + tid];
    }
    __syncthreads();
    #pragma unroll
    for (int hh = 0; hh < 2; hh++) {
        int h = tid + hh * 256;
        const float4* w4 = (const float4*)(Wa + (i64)h * NH);
        const float4* h4 = (const float4*)h1s;
        float acc = ba[h];
        for (int k = 0; k < NH / 4; k++) {
            float4 a = w4[k], x = h4[k];
            acc += a.x * x.x + a.y * x.y + a.z * x.z + a.w * x.w;
        }
        has[h] = acc;
    }
    __syncthreads();
    int wv = tid >> 6, ln = tid & 63;
    for (int p = wv; p < NP; p += 4) {
        const float* pp = proj + ((i64)b * NP + p) * NH;
        float s = 0.f;
        #pragma unroll
        for (int j = 0; j < NH / 64; j++) s += has[ln + j * 64] * pp[ln + j * 64];
        #pragma unroll
        for (int off = 32; off > 0; off >>= 1) s += __shfl_down(s, off, 64);
        if (ln == 0) sw[p] = s;
    }
    __syncthreads();
    if (tid < 64) {
        float v = (tid < NP) ? sw[tid] : -3.4e38f;
        float m = v;
        #pragma unroll
        for (int off = 32; off > 0; off >>= 1) m = fmaxf(m, __shfl_xor(m, off, 64));
        float e = (tid < NP) ? expf(v - m) : 0.f;
        float s = e;
        #pragma unroll
        for (int off = 32; off > 0; off >>= 1) s += __shfl_xor(s, off, 64);
        if (tid < NP) sw[tid] = e / s;
    }
    __syncthreads();
    #pragma unroll
    for (int hh = 0; hh < 2; hh++) {
        int h = tid + hh * 256;
        float acc = 0.f;
        for (int p = 0; p < NP; p++) acc += sw[p] * proj[((i64)b * NP + p) * NH + h];
        xa[(i64)b * 1024 + h] = acc;
    }
}

// ---------------- per-step gate GEMM (split-K 8)
struct LArgs {
    const float* A;
    const float* B1; i64 ldb1; int bo1;
    const float* B2; i64 ldb2;
    float* gpart;
};

__global__ __launch_bounds__(256) void lstm_gemm_kernel(LArgs g)
{
    __shared__ float As[16][68];
    __shared__ float Bs[16][68];
    const int tid = threadIdx.x;
    const int bn = blockIdx.x * 64;
    const int kz = blockIdx.z;
    const int tn = (tid & 15) * 4, tm = (tid >> 4) * 4;
    const int lk = tid & 15, lr = tid >> 4;
    float acc[4][4] = {};
    for (int k0 = kz * 128; k0 < kz * 128 + 128; k0 += 16) {
        #pragma unroll
        for (int i = 0; i < 4; i++) {
            int m = lr + i * 16;
            As[lk][lr + i * 16] = g.A[(i64)m * 1024 + k0 + lk];
        }
        int k = k0 + lk;
        const float* bp = (k < 512) ? (g.B1 + g.bo1 + k) : (g.B2 + (k - 512));
        i64 ldb = (k < 512) ? g.ldb1 : g.ldb2;
        #pragma unroll
        for (int i = 0; i < 4; i++) {
            int n = bn + lr + i * 16;
            Bs[lk][lr + i * 16] = bp[(i64)n * ldb];
        }
        __syncthreads();
        #pragma unroll
        for (int kk = 0; kk < 16; kk++) {
            float a[4], bv[4];
            #pragma unroll
            for (int i = 0; i < 4; i++) a[i] = As[kk][tm + i];
            #pragma unroll
            for (int j = 0; j < 4; j++) bv[j] = Bs[kk][tn + j];
            #pragma unroll
            for (int i = 0; i < 4; i++)
                #pragma unroll
                for (int j = 0; j < 4; j++) acc[i][j] += a[i] * bv[j];
        }
        __syncthreads();
    }
    float* out = g.gpart + (i64)kz * NB * NG;
    #pragma unroll
    for (int i = 0; i < 4; i++) {
        *(float4*)&out[(i64)(tm + i) * NG + bn + tn] =
            make_float4(acc[i][0], acc[i][1], acc[i][2], acc[i][3]);
    }
}

// ---------------- gate finalize
__global__ __launch_bounds__(512) void lstm_fin_kernel(
    const float* __restrict__ gpart, const float* __restrict__ xpre_t,
    const float* __restrict__ bih, const float* __restrict__ bhh,
    float* __restrict__ cbuf, float* __restrict__ hA, float* __restrict__ hB,
    float* __restrict__ h1f, __hip_bfloat16* __restrict__ h1b)
{
    int b = blockIdx.x, h = threadIdx.x;
    float gi, gf, gg, go;
    if (xpre_t) {
        const float* xp = xpre_t + (i64)b * NG;
        gi = xp[h]; gf = xp[h + 512]; gg = xp[h + 1024]; go = xp[h + 1536];
    } else {
        gi = bih[h] + bhh[h];
        gf = bih[h + 512] + bhh[h + 512];
        gg = bih[h + 1024] + bhh[h + 1024];
        go = bih[h + 1536] + bhh[h + 1536];
    }
    #pragma unroll
    for (int z = 0; z < 8; z++) {
        const float* gp = gpart + ((i64)z * NB + b) * NG;
        gi += gp[h]; gf += gp[h + 512]; gg += gp[h + 1024]; go += gp[h + 1536];
    }
    float i = sigm(gi), f = sigm(gf), g2 = tanhf(gg), o = sigm(go);
    float c = f * cbuf[(i64)b * NH + h] + i * g2;
    cbuf[(i64)b * NH + h] = c;
    float hn = o * tanhf(c);
    hA[(i64)b * 1024 + h] = hn;
    if (hB) hB[(i64)b * 1024 + h] = hn;
    if (h1f) h1f[(i64)b * NH + h] = hn;
    if (h1b) h1b[(i64)b * NH + h] = __float2bfloat16(hn);
}

// ---------------- final states
__global__ __launch_bounds__(512) void final_copy(
    const float* __restrict__ xb, const float* __restrict__ c0, const float* __restrict__ c1,
    float* __restrict__ out)
{
    int b = blockIdx.x, h = threadIdx.x;
    const i64 OB = (i64)NB * NS * NV;
    out[OB + (i64)b * NH + h] = xb[(i64)b * 1024 + h];
    out[OB + (i64)NB * NH + (i64)b * NH + h] = xb[(i64)b * 1024 + 512 + h];
    out[OB + 2 * (i64)NB * NH + (i64)b * NH + h] = c0[(i64)b * NH + h];
    out[OB + 3 * (i64)NB * NH + (i64)b * NH + h] = c1[(i64)b * NH + h];
}

extern "C" void kernel_launch(void* const* d_in, const int* in_sizes, int n_in,
                              void* d_out, int out_size, void* d_ws, size_t ws_size,
                              hipStream_t stream)
{
    (void)in_sizes; (void)n_in; (void)out_size;
    const int*   word_ids = (const int*)d_in[0];
    const float* cnn   = (const float*)d_in[1];
    const float* attnf = (const float*)d_in[2];
    const float* table = (const float*)d_in[3];
    const float* Wf    = (const float*)d_in[4];
    const float* bfp   = (const float*)d_in[5];
    const float* Wa    = (const float*)d_in[6];
    const float* ba    = (const float*)d_in[7];
    const float* Wih0  = (const float*)d_in[8];
    const float* Whh0  = (const float*)d_in[9];
    const float* bih0  = (const float*)d_in[10];
    const float* bhh0  = (const float*)d_in[11];
    const float* Wih1  = (const float*)d_in[12];
    const float* Whh1  = (const float*)d_in[13];
    const float* bih1  = (const float*)d_in[14];
    const float* bhh1  = (const float*)d_in[15];
    const float* Whi   = (const float*)d_in[16];
    const float* bhi   = (const float*)d_in[17];
    const float* Wci   = (const float*)d_in[18];
    const float* bci   = (const float*)d_in[19];
    const float* Wout  = (const float*)d_in[20];
    const float* bout  = (const float*)d_in[21];
    float* out = (float*)d_out;

    float* ws    = (float*)d_ws;
    float* proj  = ws;                    // 1,605,632
    float* xs    = proj + 1605632;        //   327,680
    float* xpre  = xs + 327680;           // 2,621,440
    float* xa    = xpre + 2621440;        //    65,536
    float* xb    = xa + 65536;            //    65,536
    float* c0    = xb + 65536;            //    32,768
    float* c1    = c0 + 32768;            //    32,768
    float* gpart = c1 + 32768;            // 1,048,576
    float* tail  = gpart + 1048576;       // = ws + 5,799,936
    // bf16 region (mfma path) or fp32 h1all (fallback)
    const i64 need_floats = 5799936 + 327680 /*h1b*/ + 7680000 /*Woutb*/;
    bool use_mfma = ws_size >= (size_t)need_floats * 4;
    __hip_bfloat16* h1b   = (__hip_bfloat16*)tail;            // 1280*512 bf16
    __hip_bfloat16* Woutb = (__hip_bfloat16*)(tail + 327680); // 30000*512 bf16
    float* h1f = tail;                                        // fallback: 655,360 floats

    init_hc<<<dim3(NB), dim3(256), 0, stream>>>(cnn, Whi, bhi, Wci, bci, xa, xb, c0, c1);
    proj_kernel<<<dim3(8, 25), dim3(256), 0, stream>>>(attnf, Wf, bfp, proj);
    embed_kernel<<<dim3(NS * NB), dim3(256), 0, stream>>>(word_ids, table, xs);
    if (use_mfma)
        cast_bf16_kernel<<<dim3(7500), dim3(256), 0, stream>>>(Wout, Woutb, NV * NH / 8);

    GArgs gx{xs, NE, Wih0, NE + NH, bih0, bhh0, xpre, NG, NS * NB, NG, NE, 0};
    gemm128_kernel<<<dim3(NG / 64, 10), dim3(256), 0, stream>>>(gx);

    float*          h1f_arg = use_mfma ? nullptr : h1f;
    __hip_bfloat16* h1b_arg = use_mfma ? h1b : nullptr;

    for (int t = 0; t < NS; t++) {
        attn_fused<<<dim3(NB), dim3(256), 0, stream>>>(
            t ? gpart : (const float*)nullptr, bih1, bhh1, c1, xb,
            t ? (h1f_arg ? h1f_arg + (i64)(t - 1) * NB * NH : nullptr) : nullptr,
            t ? (h1b_arg ? h1b_arg + (i64)(t - 1) * NB * NH : nullptr) : nullptr,
            Wa, ba, proj, xa);
        LArgs l0{xa, Wih0, NE + NH, NE, Whh0, NH, gpart};
        lstm_gemm_kernel<<<dim3(NG / 64, 1, 8), dim3(256), 0, stream>>>(l0);
        lstm_fin_kernel<<<dim3(NB), dim3(512), 0, stream>>>(
            gpart, xpre + (i64)t * NB * NG, (const float*)nullptr, (const float*)nullptr,
            c0, xb, xa + 512, (float*)nullptr, (__hip_bfloat16*)nullptr);
        LArgs l1{xb, Wih1, NH, 0, Whh1, NH, gpart};
        lstm_gemm_kernel<<<dim3(NG / 64, 1, 8), dim3(256), 0, stream>>>(l1);
    }
    // final fin1 (t = NS-1)
    lstm_fin_kernel<<<dim3(NB), dim3(512), 0, stream>>>(
        gpart, (const float*)nullptr, bih1, bhh1,
        c1, xb + 512, (float*)nullptr,
        h1f_arg ? h1f_arg + (i64)(NS - 1) * NB * NH : nullptr,
        h1b_arg ? h1b_arg + (i64)(NS - 1) * NB * NH : nullptr);

    if (use_mfma) {
        gemm_out_mfma<<<dim3(2350), dim3(256), 0, stream>>>(h1b, Woutb, bout, out);
    } else {
        GArgs go{h1f, NH, Wout, NH, bout, nullptr, out, NV, NS * NB, NV, NH, 1};
        gemm128_kernel<<<dim3((NV + 63) / 64, 10), dim3(256), 0, stream>>>(go);
    }

    final_copy<<<dim3(NB), dim3(512), 0, stream>>>(xb, c0, c1, out);
}

// Round 3
// 1636.940 us; speedup vs baseline: 1.5178x; 1.1769x over previous
//
#include <hip/hip_runtime.h>
#include <hip/hip_bf16.h>

typedef long long i64;

#define NB   64      // batch
#define NS   20      // seq
#define NV   30000   // vocab
#define NE   256     // embed
#define NH   512     // hidden
#define NF   2048    // feat
#define NP   49      // spatial
#define NG   2048    // 4*NH
#define NM   3136    // NB*NP

typedef __attribute__((ext_vector_type(8))) __bf16 bf16x8;
typedef __attribute__((ext_vector_type(4))) float  f32x4;

__device__ __forceinline__ float sigm(float x) { return 1.f / (1.f + expf(-x)); }

__device__ __forceinline__ void gload_lds16(const void* g, void* l) {
    __builtin_amdgcn_global_load_lds(
        (const __attribute__((address_space(1))) void*)g,
        (__attribute__((address_space(3))) void*)l, 16, 0, 0);
}

// ---------------- init: h_init = tanh(cnn@Whi.T+bhi), c_init = tanh(cnn@Wci.T+bci)
__global__ __launch_bounds__(256) void init_hc(
    const float* __restrict__ cnn, const float* __restrict__ Whi, const float* __restrict__ bhi,
    const float* __restrict__ Wci, const float* __restrict__ bci,
    float* __restrict__ xa, float* __restrict__ xb, float* __restrict__ c0, float* __restrict__ c1)
{
    int b = blockIdx.x, tid = threadIdx.x;
    __shared__ float xsh[NH];
    xsh[tid] = cnn[(i64)b * NH + tid];
    xsh[tid + 256] = cnn[(i64)b * NH + 256 + tid];
    __syncthreads();
    #pragma unroll
    for (int hh = 0; hh < 2; hh++) {
        int h = tid + hh * 256;
        const float4* wh = (const float4*)(Whi + (i64)h * NH);
        const float4* wc = (const float4*)(Wci + (i64)h * NH);
        const float4* xv = (const float4*)xsh;
        float ah = bhi[h], ac = bci[h];
        for (int k = 0; k < NH / 4; k++) {
            float4 x = xv[k], a = wh[k], c = wc[k];
            ah += a.x * x.x + a.y * x.y + a.z * x.z + a.w * x.w;
            ac += c.x * x.x + c.y * x.y + c.z * x.z + c.w * x.w;
        }
        float th = tanhf(ah), tc = tanhf(ac);
        xa[(i64)b * 1024 + 512 + h] = th;
        xb[(i64)b * 1024 + 512 + h] = th;
        c0[(i64)b * NH + h] = tc;
        c1[(i64)b * NH + h] = tc;
    }
}

// ---------------- embedding gather
__global__ __launch_bounds__(256) void embed_kernel(
    const int* __restrict__ ids, const float* __restrict__ table, float* __restrict__ xs)
{
    int blk = blockIdx.x;            // t*NB + b
    int t = blk / NB, b = blk % NB;
    int id = ids[(i64)b * NS + t];
    float v = (id == 0) ? 0.f : table[(i64)id * NE + threadIdx.x];
    xs[(i64)blk * NE + threadIdx.x] = v;
}

// ---------------- fp32 -> bf16 cast (8 elems/thread), same layout
__global__ __launch_bounds__(256) void cast_bf16_kernel(
    const float* __restrict__ in, __hip_bfloat16* __restrict__ outp, int n8)
{
    int i = blockIdx.x * 256 + threadIdx.x;
    if (i >= n8) return;
    const float4* p = (const float4*)(in + (i64)i * 8);
    float4 a = p[0], b = p[1];
    __hip_bfloat16 v[8];
    v[0] = __float2bfloat16(a.x); v[1] = __float2bfloat16(a.y);
    v[2] = __float2bfloat16(a.z); v[3] = __float2bfloat16(a.w);
    v[4] = __float2bfloat16(b.x); v[5] = __float2bfloat16(b.y);
    v[6] = __float2bfloat16(b.z); v[7] = __float2bfloat16(b.w);
    *(float4*)(outp + (i64)i * 8) = *(float4*)v;
}

// ---------------- transpose-cast: attnf (B,F,49) -> featT (B*49, F) bf16
// block = (b, f0/64); LDS tile [64 f][49 p] with stride 51 (conflict-free).
__global__ __launch_bounds__(256) void tcast_kernel(
    const float* __restrict__ af, __hip_bfloat16* __restrict__ featT)
{
    int b = blockIdx.x >> 5;
    int f0 = (blockIdx.x & 31) * 64;
    __shared__ float t[64][51];
    int tid = threadIdx.x;
    for (int idx = tid; idx < 64 * NP; idx += 256) {
        int f = idx / NP, p = idx - f * NP;
        t[f][p] = af[((i64)b * NF + f0 + f) * NP + p];
    }
    __syncthreads();
    for (int idx = tid; idx < NP * 64; idx += 256) {
        int p = idx >> 6, f = idx & 63;
        featT[((i64)b * NP + p) * NF + f0 + f] = __float2bfloat16(t[f][p]);
    }
}

// ---------------- proj bf16 MFMA: proj[m][n] = featT[m][:] . Wfb[n][:] + bf[n]
// M=3136 (25 tiles), N=512 (4 tiles), K=2048, BM=BN=128, BK=64.
__global__ __launch_bounds__(256) void proj_mfma(
    const __hip_bfloat16* __restrict__ At_, const __hip_bfloat16* __restrict__ Wb_,
    const float* __restrict__ bf, float* __restrict__ proj)
{
    __shared__ __bf16 As[128 * 64];
    __shared__ __bf16 Bs[128 * 64];
    const __bf16* At = (const __bf16*)At_;
    const __bf16* Wb = (const __bf16*)Wb_;
    const int wgid = blockIdx.x;
    const int bm = (wgid % 25) * 128;
    const int bn = (wgid / 25) * 128;
    const int tid = threadIdx.x;
    const int w = tid >> 6, l = tid & 63;
    const int wr = w >> 1, wc = w & 1;
    f32x4 acc[4][4] = {};
    for (int k0 = 0; k0 < NF; k0 += 64) {
        #pragma unroll
        for (int r = 0; r < 4; r++) {
            int rowA = bm + r * 32 + w * 8 + (l >> 3);
            if (rowA >= NM) rowA = 0;
            gload_lds16(At + (i64)rowA * NF + k0 + (l & 7) * 8, &As[(r * 32 + w * 8) * 64]);
            int rowB = bn + r * 32 + w * 8 + (l >> 3);
            gload_lds16(Wb + (i64)rowB * NF + k0 + (l & 7) * 8, &Bs[(r * 32 + w * 8) * 64]);
        }
        __syncthreads();
        #pragma unroll
        for (int kk = 0; kk < 2; kk++) {
            bf16x8 af[4], bfr[4];
            #pragma unroll
            for (int mr = 0; mr < 4; mr++)
                af[mr] = *(const bf16x8*)&As[(wr * 64 + mr * 16 + (l & 15)) * 64 + kk * 32 + (l >> 4) * 8];
            #pragma unroll
            for (int nr = 0; nr < 4; nr++)
                bfr[nr] = *(const bf16x8*)&Bs[(wc * 64 + nr * 16 + (l & 15)) * 64 + kk * 32 + (l >> 4) * 8];
            #pragma unroll
            for (int mr = 0; mr < 4; mr++)
                #pragma unroll
                for (int nr = 0; nr < 4; nr++)
                    acc[mr][nr] = __builtin_amdgcn_mfma_f32_16x16x32_bf16(af[mr], bfr[nr], acc[mr][nr], 0, 0, 0);
        }
        __syncthreads();
    }
    #pragma unroll
    for (int nr = 0; nr < 4; nr++) {
        int n = bn + wc * 64 + nr * 16 + (l & 15);
        float bv = bf[n];
        #pragma unroll
        for (int mr = 0; mr < 4; mr++) {
            int mbase = bm + wr * 64 + mr * 16 + (l >> 4) * 4;
            #pragma unroll
            for (int j = 0; j < 4; j++) {
                int m = mbase + j;
                if (m < NM) proj[(i64)m * NH + n] = acc[mr][nr][j] + bv;
            }
        }
    }
}

// ---------------- fp32 proj GEMM (fallback only)
__global__ __launch_bounds__(256) void proj_kernel(
    const float* __restrict__ af, const float* __restrict__ Wf,
    const float* __restrict__ bf, float* __restrict__ proj)
{
    __shared__ float As[16][132];
    __shared__ float Bs[16][68];
    const int tid = threadIdx.x;
    const int bn = blockIdx.x * 64;
    const int bm = blockIdx.y * 128;
    const int tn = (tid & 15) * 4, tm = (tid >> 4) * 8;
    const int lk = tid & 15, lr = tid >> 4;
    const int lm = tid & 127, lkq = tid >> 7;
    const int m_g = bm + lm;
    const int bA = m_g / NP, pA = m_g - bA * NP;
    float acc[8][4] = {};
    for (int k0 = 0; k0 < NF; k0 += 16) {
        #pragma unroll
        for (int i = 0; i < 8; i++) {
            int kk = lkq * 8 + i;
            As[kk][lm] = (m_g < NM) ? af[(i64)bA * (NF * NP) + (i64)(k0 + kk) * NP + pA] : 0.f;
        }
        #pragma unroll
        for (int i = 0; i < 4; i++) {
            int n = bn + lr + i * 16;
            Bs[lk][lr + i * 16] = Wf[(i64)n * NF + k0 + lk];
        }
        __syncthreads();
        #pragma unroll
        for (int kk = 0; kk < 16; kk++) {
            float a[8], bv[4];
            #pragma unroll
            for (int i = 0; i < 8; i++) a[i] = As[kk][tm + i];
            #pragma unroll
            for (int j = 0; j < 4; j++) bv[j] = Bs[kk][tn + j];
            #pragma unroll
            for (int i = 0; i < 8; i++)
                #pragma unroll
                for (int j = 0; j < 4; j++) acc[i][j] += a[i] * bv[j];
        }
        __syncthreads();
    }
    #pragma unroll
    for (int i = 0; i < 8; i++) {
        int m = bm + tm + i;
        if (m < NM) {
            #pragma unroll
            for (int j = 0; j < 4; j++) {
                int n = bn + tn + j;
                proj[(i64)m * NH + n] = acc[i][j] + bf[n];
            }
        }
    }
}

// ---------------- generic fp32 GEMM C = A @ B.T (+bias)
struct GArgs {
    const float* A; i64 lda;
    const float* Bm; i64 ldb;
    const float* bias1; const float* bias2;
    float* C; i64 ldc;
    int M, N, K, outmode;
};

__global__ __launch_bounds__(256) void gemm128_kernel(GArgs g)
{
    __shared__ float As[16][132];
    __shared__ float Bs[16][68];
    const int tid = threadIdx.x;
    const int bn = blockIdx.x * 64;
    const int bm = blockIdx.y * 128;
    const int tn = (tid & 15) * 4, tm = (tid >> 4) * 8;
    const int lk = tid & 15, lr = tid >> 4;
    float acc[8][4] = {};
    for (int k0 = 0; k0 < g.K; k0 += 16) {
        #pragma unroll
        for (int i = 0; i < 8; i++) {
            int m = bm + lr + i * 16;
            As[lk][lr + i * 16] = (m < g.M) ? g.A[(i64)m * g.lda + k0 + lk] : 0.f;
        }
        #pragma unroll
        for (int i = 0; i < 4; i++) {
            int n = bn + lr + i * 16;
            Bs[lk][lr + i * 16] = (n < g.N) ? g.Bm[(i64)n * g.ldb + k0 + lk] : 0.f;
        }
        __syncthreads();
        #pragma unroll
        for (int kk = 0; kk < 16; kk++) {
            float a[8], bv[4];
            #pragma unroll
            for (int i = 0; i < 8; i++) a[i] = As[kk][tm + i];
            #pragma unroll
            for (int j = 0; j < 4; j++) bv[j] = Bs[kk][tn + j];
            #pragma unroll
            for (int i = 0; i < 8; i++)
                #pragma unroll
                for (int j = 0; j < 4; j++) acc[i][j] += a[i] * bv[j];
        }
        __syncthreads();
    }
    #pragma unroll
    for (int i = 0; i < 8; i++) {
        int m = bm + tm + i;
        if (m >= g.M) continue;
        int n0 = bn + tn;
        float v[4];
        #pragma unroll
        for (int j = 0; j < 4; j++) {
            v[j] = acc[i][j];
            int n = n0 + j;
            if (n < g.N) {
                if (g.bias1) v[j] += g.bias1[n];
                if (g.bias2) v[j] += g.bias2[n];
            }
        }
        i64 base = g.outmode ? (i64)(m & 63) * ((i64)NS * NV) + (i64)(m >> 6) * NV + n0
                             : (i64)m * g.ldc + n0;
        if (n0 + 3 < g.N) {
            *(float4*)&g.C[base] = make_float4(v[0], v[1], v[2], v[3]);
        } else {
            #pragma unroll
            for (int j = 0; j < 4; j++)
                if (n0 + j < g.N) g.C[base + j] = v[j];
        }
    }
}

// ---------------- phase-C bf16 MFMA GEMM (out proj, 128x128 tiles, XCD swizzle)
__global__ __launch_bounds__(256) void gemm_out_mfma(
    const __hip_bfloat16* __restrict__ Ab_, const __hip_bfloat16* __restrict__ Wb_,
    const float* __restrict__ bout, float* __restrict__ out)
{
    __shared__ __bf16 As[128 * 64];
    __shared__ __bf16 Bs[128 * 64];
    const __bf16* Ab = (const __bf16*)Ab_;
    const __bf16* Wb = (const __bf16*)Wb_;
    int orig = blockIdx.x;
    int xcd = orig & 7, local = orig >> 3;
    int wgid = (xcd < 6 ? xcd * 294 : 6 * 294 + (xcd - 6) * 293) + local;
    const int bn = (wgid / 10) * 128;
    const int bm = (wgid % 10) * 128;
    const int tid = threadIdx.x;
    const int w = tid >> 6;
    const int l = tid & 63;
    const int wr = w >> 1, wc = w & 1;
    f32x4 acc[4][4] = {};
    for (int k0 = 0; k0 < NH; k0 += 64) {
        #pragma unroll
        for (int r = 0; r < 4; r++) {
            int rowA = r * 32 + w * 8 + (l >> 3);
            const __bf16* srcA = Ab + (i64)(bm + rowA) * NH + k0 + (l & 7) * 8;
            gload_lds16(srcA, &As[(r * 32 + w * 8) * 64]);
            int rowBn = bn + r * 32 + w * 8 + (l >> 3);
            if (rowBn >= NV) rowBn = 0;
            const __bf16* srcB = Wb + (i64)rowBn * NH + k0 + (l & 7) * 8;
            gload_lds16(srcB, &Bs[(r * 32 + w * 8) * 64]);
        }
        __syncthreads();
        #pragma unroll
        for (int kk = 0; kk < 2; kk++) {
            bf16x8 af[4], bfr[4];
            #pragma unroll
            for (int mr = 0; mr < 4; mr++)
                af[mr] = *(const bf16x8*)&As[(wr * 64 + mr * 16 + (l & 15)) * 64 + kk * 32 + (l >> 4) * 8];
            #pragma unroll
            for (int nr = 0; nr < 4; nr++)
                bfr[nr] = *(const bf16x8*)&Bs[(wc * 64 + nr * 16 + (l & 15)) * 64 + kk * 32 + (l >> 4) * 8];
            #pragma unroll
            for (int mr = 0; mr < 4; mr++)
                #pragma unroll
                for (int nr = 0; nr < 4; nr++)
                    acc[mr][nr] = __builtin_amdgcn_mfma_f32_16x16x32_bf16(af[mr], bfr[nr], acc[mr][nr], 0, 0, 0);
        }
        __syncthreads();
    }
    #pragma unroll
    for (int nr = 0; nr < 4; nr++) {
        int n = bn + wc * 64 + nr * 16 + (l & 15);
        if (n >= NV) continue;
        float bv = bout[n];
        #pragma unroll
        for (int mr = 0; mr < 4; mr++) {
            int mbase = bm + wr * 64 + mr * 16 + (l >> 4) * 4;
            #pragma unroll
            for (int j = 0; j < 4; j++) {
                int m = mbase + j;   // m = t*64+b
                out[(i64)(m & 63) * ((i64)NS * NV) + (i64)(m >> 6) * NV + n] = acc[mr][nr][j] + bv;
            }
        }
    }
}

// ---------------- fused: [fin1 of prev step] + attention
__global__ __launch_bounds__(256) void attn_fused(
    const float* __restrict__ gpart,
    const float* __restrict__ bih1, const float* __restrict__ bhh1,
    float* __restrict__ c1, float* __restrict__ xb,
    float* __restrict__ h1f, __hip_bfloat16* __restrict__ h1b,
    const float* __restrict__ Wa, const float* __restrict__ ba,
    const float* __restrict__ proj, float* __restrict__ xa)
{
    int b = blockIdx.x, tid = threadIdx.x;
    __shared__ float h1s[NH];
    __shared__ float has[NH];
    __shared__ float sw[64];
    if (gpart) {
        #pragma unroll
        for (int hh = 0; hh < 2; hh++) {
            int h = tid + hh * 256;
            float gi = bih1[h] + bhh1[h];
            float gf = bih1[h + 512] + bhh1[h + 512];
            float gg = bih1[h + 1024] + bhh1[h + 1024];
            float go = bih1[h + 1536] + bhh1[h + 1536];
            #pragma unroll
            for (int z = 0; z < 8; z++) {
                const float* gp = gpart + ((i64)z * NB + b) * NG;
                gi += gp[h]; gf += gp[h + 512]; gg += gp[h + 1024]; go += gp[h + 1536];
            }
            float i = sigm(gi), f = sigm(gf), g2 = tanhf(gg), o = sigm(go);
            float c = f * c1[(i64)b * NH + h] + i * g2;
            c1[(i64)b * NH + h] = c;
            float hn = o * tanhf(c);
            h1s[h] = hn;
            xb[(i64)b * 1024 + 512 + h] = hn;
            if (h1f) h1f[(i64)b * NH + h] = hn;
            if (h1b) h1b[(i64)b * NH + h] = __float2bfloat16(hn);
        }
    } else {
        h1s[tid] = xb[(i64)b * 1024 + 512 + tid];
        h1s[tid + 256] = xb[(i64)b * 1024 + 768 + tid];
    }
    __syncthreads();
    #pragma unroll
    for (int hh = 0; hh < 2; hh++) {
        int h = tid + hh * 256;
        const float4* w4 = (const float4*)(Wa + (i64)h * NH);
        const float4* h4 = (const float4*)h1s;
        float acc = ba[h];
        for (int k = 0; k < NH / 4; k++) {
            float4 a = w4[k], x = h4[k];
            acc += a.x * x.x + a.y * x.y + a.z * x.z + a.w * x.w;
        }
        has[h] = acc;
    }
    __syncthreads();
    int wv = tid >> 6, ln = tid & 63;
    for (int p = wv; p < NP; p += 4) {
        const float* pp = proj + ((i64)b * NP + p) * NH;
        float s = 0.f;
        #pragma unroll
        for (int j = 0; j < NH / 64; j++) s += has[ln + j * 64] * pp[ln + j * 64];
        #pragma unroll
        for (int off = 32; off > 0; off >>= 1) s += __shfl_down(s, off, 64);
        if (ln == 0) sw[p] = s;
    }
    __syncthreads();
    if (tid < 64) {
        float v = (tid < NP) ? sw[tid] : -3.4e38f;
        float m = v;
        #pragma unroll
        for (int off = 32; off > 0; off >>= 1) m = fmaxf(m, __shfl_xor(m, off, 64));
        float e = (tid < NP) ? expf(v - m) : 0.f;
        float s = e;
        #pragma unroll
        for (int off = 32; off > 0; off >>= 1) s += __shfl_xor(s, off, 64);
        if (tid < NP) sw[tid] = e / s;
    }
    __syncthreads();
    #pragma unroll
    for (int hh = 0; hh < 2; hh++) {
        int h = tid + hh * 256;
        float acc = 0.f;
        for (int p = 0; p < NP; p++) acc += sw[p] * proj[((i64)b * NP + p) * NH + h];
        xa[(i64)b * 1024 + h] = acc;
    }
}

// ---------------- per-step gate GEMM (split-K 8)
struct LArgs {
    const float* A;
    const float* B1; i64 ldb1; int bo1;
    const float* B2; i64 ldb2;
    float* gpart;
};

__global__ __launch_bounds__(256) void lstm_gemm_kernel(LArgs g)
{
    __shared__ float As[16][68];
    __shared__ float Bs[16][68];
    const int tid = threadIdx.x;
    const int bn = blockIdx.x * 64;
    const int kz = blockIdx.z;
    const int tn = (tid & 15) * 4, tm = (tid >> 4) * 4;
    const int lk = tid & 15, lr = tid >> 4;
    float acc[4][4] = {};
    for (int k0 = kz * 128; k0 < kz * 128 + 128; k0 += 16) {
        #pragma unroll
        for (int i = 0; i < 4; i++) {
            int m = lr + i * 16;
            As[lk][lr + i * 16] = g.A[(i64)m * 1024 + k0 + lk];
        }
        int k = k0 + lk;
        const float* bp = (k < 512) ? (g.B1 + g.bo1 + k) : (g.B2 + (k - 512));
        i64 ldb = (k < 512) ? g.ldb1 : g.ldb2;
        #pragma unroll
        for (int i = 0; i < 4; i++) {
            int n = bn + lr + i * 16;
            Bs[lk][lr + i * 16] = bp[(i64)n * ldb];
        }
        __syncthreads();
        #pragma unroll
        for (int kk = 0; kk < 16; kk++) {
            float a[4], bv[4];
            #pragma unroll
            for (int i = 0; i < 4; i++) a[i] = As[kk][tm + i];
            #pragma unroll
            for (int j = 0; j < 4; j++) bv[j] = Bs[kk][tn + j];
            #pragma unroll
            for (int i = 0; i < 4; i++)
                #pragma unroll
                for (int j = 0; j < 4; j++) acc[i][j] += a[i] * bv[j];
        }
        __syncthreads();
    }
    float* out = g.gpart + (i64)kz * NB * NG;
    #pragma unroll
    for (int i = 0; i < 4; i++) {
        *(float4*)&out[(i64)(tm + i) * NG + bn + tn] =
            make_float4(acc[i][0], acc[i][1], acc[i][2], acc[i][3]);
    }
}

// ---------------- gate finalize
__global__ __launch_bounds__(512) void lstm_fin_kernel(
    const float* __restrict__ gpart, const float* __restrict__ xpre_t,
    const float* __restrict__ bih, const float* __restrict__ bhh,
    float* __restrict__ cbuf, float* __restrict__ hA, float* __restrict__ hB,
    float* __restrict__ h1f, __hip_bfloat16* __restrict__ h1b)
{
    int b = blockIdx.x, h = threadIdx.x;
    float gi, gf, gg, go;
    if (xpre_t) {
        const float* xp = xpre_t + (i64)b * NG;
        gi = xp[h]; gf = xp[h + 512]; gg = xp[h + 1024]; go = xp[h + 1536];
    } else {
        gi = bih[h] + bhh[h];
        gf = bih[h + 512] + bhh[h + 512];
        gg = bih[h + 1024] + bhh[h + 1024];
        go = bih[h + 1536] + bhh[h + 1536];
    }
    #pragma unroll
    for (int z = 0; z < 8; z++) {
        const float* gp = gpart + ((i64)z * NB + b) * NG;
        gi += gp[h]; gf += gp[h + 512]; gg += gp[h + 1024]; go += gp[h + 1536];
    }
    float i = sigm(gi), f = sigm(gf), g2 = tanhf(gg), o = sigm(go);
    float c = f * cbuf[(i64)b * NH + h] + i * g2;
    cbuf[(i64)b * NH + h] = c;
    float hn = o * tanhf(c);
    hA[(i64)b * 1024 + h] = hn;
    if (hB) hB[(i64)b * 1024 + h] = hn;
    if (h1f) h1f[(i64)b * NH + h] = hn;
    if (h1b) h1b[(i64)b * NH + h] = __float2bfloat16(hn);
}

// ---------------- final states
__global__ __launch_bounds__(512) void final_copy(
    const float* __restrict__ xb, const float* __restrict__ c0, const float* __restrict__ c1,
    float* __restrict__ out)
{
    int b = blockIdx.x, h = threadIdx.x;
    const i64 OB = (i64)NB * NS * NV;
    out[OB + (i64)b * NH + h] = xb[(i64)b * 1024 + h];
    out[OB + (i64)NB * NH + (i64)b * NH + h] = xb[(i64)b * 1024 + 512 + h];
    out[OB + 2 * (i64)NB * NH + (i64)b * NH + h] = c0[(i64)b * NH + h];
    out[OB + 3 * (i64)NB * NH + (i64)b * NH + h] = c1[(i64)b * NH + h];
}

extern "C" void kernel_launch(void* const* d_in, const int* in_sizes, int n_in,
                              void* d_out, int out_size, void* d_ws, size_t ws_size,
                              hipStream_t stream)
{
    (void)in_sizes; (void)n_in; (void)out_size;
    const int*   word_ids = (const int*)d_in[0];
    const float* cnn   = (const float*)d_in[1];
    const float* attnf = (const float*)d_in[2];
    const float* table = (const float*)d_in[3];
    const float* Wf    = (const float*)d_in[4];
    const float* bfp   = (const float*)d_in[5];
    const float* Wa    = (const float*)d_in[6];
    const float* ba    = (const float*)d_in[7];
    const float* Wih0  = (const float*)d_in[8];
    const float* Whh0  = (const float*)d_in[9];
    const float* bih0  = (const float*)d_in[10];
    const float* bhh0  = (const float*)d_in[11];
    const float* Wih1  = (const float*)d_in[12];
    const float* Whh1  = (const float*)d_in[13];
    const float* bih1  = (const float*)d_in[14];
    const float* bhh1  = (const float*)d_in[15];
    const float* Whi   = (const float*)d_in[16];
    const float* bhi   = (const float*)d_in[17];
    const float* Wci   = (const float*)d_in[18];
    const float* bci   = (const float*)d_in[19];
    const float* Wout  = (const float*)d_in[20];
    const float* bout  = (const float*)d_in[21];
    float* out = (float*)d_out;

    float* ws    = (float*)d_ws;
    // persistent across the loop:
    float* proj  = ws;                    // 1,605,632
    float* xs    = proj + 1605632;        //   327,680
    float* xpre  = xs + 327680;           // 2,621,440
    float* xa    = xpre + 2621440;        //    65,536
    float* xb    = xa + 65536;            //    65,536
    float* c0    = xb + 65536;            //    32,768
    float* c1    = c0 + 32768;            //    32,768
    float* gpart = c1 + 32768;            // 1,048,576
    float* h1bf  = gpart + 1048576;       //   327,680 (h1 bf16, or h1 fp32 fallback needs 655,360)
    float* tail  = h1bf + 655360;         // = ws + 6,455,296 (reserve fp32-fallback size)
    // tail region, phase-aliased:
    //   prep : featT (3,211,264 fl) + Wfb (524,288 fl) = 3,735,552
    //   end  : Woutb (7,680,000 fl)
    const i64 need_floats = 6455296 + 7680000;       // 14,135,296 fl = 56.5 MB
    bool use_mfma = ws_size >= (size_t)need_floats * 4;
    __hip_bfloat16* h1b   = (__hip_bfloat16*)h1bf;
    __hip_bfloat16* featT = (__hip_bfloat16*)tail;
    __hip_bfloat16* Wfb   = (__hip_bfloat16*)(tail + 3211264);
    __hip_bfloat16* Woutb = (__hip_bfloat16*)tail;
    float* h1f = h1bf;   // fallback: fp32 h1all (fits in reserved 655,360)

    init_hc<<<dim3(NB), dim3(256), 0, stream>>>(cnn, Whi, bhi, Wci, bci, xa, xb, c0, c1);

    if (use_mfma) {
        tcast_kernel<<<dim3(NB * 32), dim3(256), 0, stream>>>(attnf, featT);
        cast_bf16_kernel<<<dim3(512), dim3(256), 0, stream>>>(Wf, Wfb, NH * NF / 8);
        proj_mfma<<<dim3(100), dim3(256), 0, stream>>>(featT, Wfb, bfp, proj);
        // after proj_mfma, featT/Wfb are dead -> cast Wout into the same region
        cast_bf16_kernel<<<dim3(7500), dim3(256), 0, stream>>>(Wout, Woutb, NV * NH / 8);
    } else {
        proj_kernel<<<dim3(8, 25), dim3(256), 0, stream>>>(attnf, Wf, bfp, proj);
    }

    embed_kernel<<<dim3(NS * NB), dim3(256), 0, stream>>>(word_ids, table, xs);
    GArgs gx{xs, NE, Wih0, NE + NH, bih0, bhh0, xpre, NG, NS * NB, NG, NE, 0};
    gemm128_kernel<<<dim3(NG / 64, 10), dim3(256), 0, stream>>>(gx);

    float*          h1f_arg = use_mfma ? nullptr : h1f;
    __hip_bfloat16* h1b_arg = use_mfma ? h1b : nullptr;

    for (int t = 0; t < NS; t++) {
        attn_fused<<<dim3(NB), dim3(256), 0, stream>>>(
            t ? gpart : (const float*)nullptr, bih1, bhh1, c1, xb,
            t ? (h1f_arg ? h1f_arg + (i64)(t - 1) * NB * NH : nullptr) : nullptr,
            t ? (h1b_arg ? h1b_arg + (i64)(t - 1) * NB * NH : nullptr) : nullptr,
            Wa, ba, proj, xa);
        LArgs l0{xa, Wih0, NE + NH, NE, Whh0, NH, gpart};
        lstm_gemm_kernel<<<dim3(NG / 64, 1, 8), dim3(256), 0, stream>>>(l0);
        lstm_fin_kernel<<<dim3(NB), dim3(512), 0, stream>>>(
            gpart, xpre + (i64)t * NB * NG, (const float*)nullptr, (const float*)nullptr,
            c0, xb, xa + 512, (float*)nullptr, (__hip_bfloat16*)nullptr);
        LArgs l1{xb, Wih1, NH, 0, Whh1, NH, gpart};
        lstm_gemm_kernel<<<dim3(NG / 64, 1, 8), dim3(256), 0, stream>>>(l1);
    }
    lstm_fin_kernel<<<dim3(NB), dim3(512), 0, stream>>>(
        gpart, (const float*)nullptr, bih1, bhh1,
        c1, xb + 512, (float*)nullptr,
        h1f_arg ? h1f_arg + (i64)(NS - 1) * NB * NH : nullptr,
        h1b_arg ? h1b_arg + (i64)(NS - 1) * NB * NH : nullptr);

    if (use_mfma) {
        gemm_out_mfma<<<dim3(2350), dim3(256), 0, stream>>>(h1b, Woutb, bout, out);
    } else {
        GArgs go{h1f, NH, Wout, NH, bout, nullptr, out, NV, NS * NB, NV, NH, 1};
        gemm128_kernel<<<dim3((NV + 63) / 64, 10), dim3(256), 0, stream>>>(go);
    }

    final_copy<<<dim3(NB), dim3(512), 0, stream>>>(xb, c0, c1, out);
}